// Round 9
// baseline (314.007 us; speedup 1.0000x reference)
//
#include <hip/hip_runtime.h>
#include <hip/hip_bf16.h>
#include <math.h>

// GCN 2-layer: x[N,128] @ W1 -> agg -> relu -> @ W2 -> agg -> log_softmax
// N=100000, E=1600000, F=128, H=64, C=40
// CSR via LDS bucket counting-sort (zero global atomics).
// Layer 2 reordered: A@(y@W2) == (A@y)@W2 -> aggregate 64-wide bf16 y
// (full-wave gather), then dense gemm2+log_softmax streaming kernel.

#define NFEAT 128
#define HID 64
#define NCLS 40
#define PB 512          // partition blocks for hist/bucketize
#define BSH 7           // 128 nodes per bucket
#define NBUK_MAX 1024

static __device__ __forceinline__ unsigned short f2bf(float f) {
    unsigned u = __float_as_uint(f);
    unsigned r = (u + 0x7fffu + ((u >> 16) & 1u)) >> 16;
    return (unsigned short)r;
}
static __device__ __forceinline__ float bf2f(unsigned short b) {
    return __uint_as_float(((unsigned)b) << 16);
}

// ---------- Pass A: per-block bucket histogram ----------
__global__ __launch_bounds__(256) void k_hist(const int* __restrict__ dst,
                                              int* __restrict__ ghist,
                                              int e, int nbuk, int epb) {
    __shared__ int hist[NBUK_MAX];
    for (int j = threadIdx.x; j < nbuk; j += 256) hist[j] = 0;
    __syncthreads();
    int b = blockIdx.x;
    int lo = b * epb, hi = min(lo + epb, e);
    for (int i = lo + threadIdx.x; i < hi; i += 256)
        atomicAdd(&hist[dst[i] >> BSH], 1);
    __syncthreads();
    for (int j = threadIdx.x; j < nbuk; j += 256) ghist[j * PB + b] = hist[j];
}

// ---------- Pass B1: exclusive scan of each bucket's column (in place) ----------
__global__ __launch_bounds__(256) void k_colscan(int* __restrict__ ghist,
                                                 int* __restrict__ buktot, int nbuk) {
    __shared__ int s[256];
    int k = blockIdx.x, t = threadIdx.x;
    int* col = ghist + k * PB;
    int v0 = col[2 * t], v1 = col[2 * t + 1];
    int sum = v0 + v1;
    s[t] = sum; __syncthreads();
    for (int off = 1; off < 256; off <<= 1) {
        int x = (t >= off) ? s[t - off] : 0;
        __syncthreads();
        s[t] += x;
        __syncthreads();
    }
    int excl = s[t] - sum;
    col[2 * t] = excl;
    col[2 * t + 1] = excl + v0;
    if (t == 255) buktot[k] = s[255];
}

// ---------- Pass B2: scan bucket totals -> bukstart ----------
__global__ __launch_bounds__(256) void k_bukscan(const int* __restrict__ buktot,
                                                 int* __restrict__ bukstart,
                                                 int* __restrict__ rowptr,
                                                 int nbuk, int n, int e) {
    __shared__ int s[256];
    int t = threadIdx.x;
    int v[4]; int sum = 0;
#pragma unroll
    for (int j = 0; j < 4; j++) { int idx = t * 4 + j; v[j] = (idx < nbuk) ? buktot[idx] : 0; sum += v[j]; }
    s[t] = sum; __syncthreads();
    for (int off = 1; off < 256; off <<= 1) {
        int x = (t >= off) ? s[t - off] : 0;
        __syncthreads();
        s[t] += x;
        __syncthreads();
    }
    int excl = s[t] - sum;
#pragma unroll
    for (int j = 0; j < 4; j++) { int idx = t * 4 + j; if (idx < nbuk) bukstart[idx] = excl; excl += v[j]; }
    if (t == 255) bukstart[nbuk] = s[255];
    if (t == 0) rowptr[n] = e;
}

// ---------- Pass C: scatter edges into bucket-sorted order (LDS atomics only) ----------
__global__ __launch_bounds__(256) void k_bucketize(const int* __restrict__ src,
                                                   const int* __restrict__ dst,
                                                   const float* __restrict__ w,
                                                   const int* __restrict__ ghist,
                                                   const int* __restrict__ bukstart,
                                                   unsigned long long* __restrict__ sedge,
                                                   int e, int nbuk, int epb) {
    __shared__ int loff[NBUK_MAX];
    int b = blockIdx.x;
    for (int j = threadIdx.x; j < nbuk; j += 256) loff[j] = bukstart[j] + ghist[j * PB + b];
    __syncthreads();
    int lo = b * epb, hi = min(lo + epb, e);
    for (int i = lo + threadIdx.x; i < hi; i += 256) {
        int d = dst[i], s = src[i];
        int k = d >> BSH;
        int pos = atomicAdd(&loff[k], 1);
        unsigned long long rec = ((unsigned long long)__float_as_uint(w[i]) << 32)
                               | ((unsigned)(d & 127) << 17) | (unsigned)s;
        sedge[pos] = rec;
    }
}

// ---------- Pass D: per-bucket CSR + degree (LDS float adds) ----------
__global__ __launch_bounds__(256) void k_bucket_csr(const unsigned long long* __restrict__ sedge,
                                                    const int* __restrict__ bukstart,
                                                    int* __restrict__ rowptr,
                                                    float* __restrict__ dinv,
                                                    int2* __restrict__ edges, int n) {
    __shared__ int cnt[128]; __shared__ float wsum[128];
    __shared__ int fill[128]; __shared__ int rloc[128];
    int k = blockIdx.x, t = threadIdx.x;
    int base = k << BSH;
    int nloc = n - base; if (nloc > 128) nloc = 128;
    if (t < 128) { cnt[t] = 0; fill[t] = 0; wsum[t] = 1.0f; }   // 1.0 = self-loop weight
    __syncthreads();
    int lo = bukstart[k], hi = bukstart[k + 1];
    for (int p = lo + t; p < hi; p += 256) {
        unsigned long long r = sedge[p];
        int dloc = (int)((r >> 17) & 127);
        atomicAdd(&cnt[dloc], 1);
        atomicAdd(&wsum[dloc], __uint_as_float((unsigned)(r >> 32)));
    }
    __syncthreads();
    if (t < 128) rloc[t] = cnt[t];
    __syncthreads();
    for (int off = 1; off < 128; off <<= 1) {
        int x = 0;
        if (t < 128 && t >= off) x = rloc[t - off];
        __syncthreads();
        if (t < 128) rloc[t] += x;
        __syncthreads();
    }
    if (t < 128) {
        int excl = rloc[t] - cnt[t];
        rloc[t] = excl;
        if (t < nloc) {
            rowptr[base + t] = lo + excl;
            dinv[base + t] = rsqrtf(wsum[t]);   // deg >= 1 (self loop)
        }
    }
    __syncthreads();
    for (int p = lo + t; p < hi; p += 256) {
        unsigned long long r = sedge[p];
        int dloc = (int)((r >> 17) & 127);
        int srcn = (int)(r & 0x1ffff);
        int pos = lo + rloc[dloc] + atomicAdd(&fill[dloc], 1);
        edges[pos] = make_int2((dloc << 17) | srcn, (int)(unsigned)(r >> 32)); // keep dloc+raw w
    }
}

// ---------- Pass E: normalize edge values in place ----------
__global__ __launch_bounds__(256) void k_norm(const int* __restrict__ bukstart,
                                              const float* __restrict__ dinv,
                                              int2* __restrict__ edges, int n) {
    int k = blockIdx.x;
    int base = k << BSH;
    int lo = bukstart[k], hi = bukstart[k + 1];
    for (int p = lo + threadIdx.x; p < hi; p += 256) {
        int2 rec = edges[p];
        int dloc = rec.x >> 17, srcn = rec.x & 0x1ffff;
        float v = __int_as_float(rec.y) * dinv[srcn] * dinv[base + dloc];
        edges[p] = make_int2(srcn, __float_as_int(v));
    }
}

// ---------- GEMM1: 64-row tiles, x transposed in LDS, bf16 output ----------
__global__ __launch_bounds__(256) void k_gemm1(const float* __restrict__ x,
                                               const float* __restrict__ W1,
                                               unsigned short* __restrict__ h1, int n) {
    __shared__ float xs[64 * 65];
    int t = threadIdx.x;
    int lane = t & 63;
    int wid = __builtin_amdgcn_readfirstlane(t >> 6);
    int base = blockIdx.x * 64;
    int nrows = n - base; if (nrows > 64) nrows = 64;
    const float4* xg = reinterpret_cast<const float4*>(x + (size_t)base * NFEAT);
    float acc[16];
#pragma unroll
    for (int c = 0; c < 16; c++) acc[c] = 0.f;
#pragma unroll
    for (int h = 0; h < 2; h++) {
        for (int j = t; j < nrows * 16; j += 256) {
            int row = j >> 4, k4 = j & 15;
            float4 v = xg[row * 32 + h * 16 + k4];
            xs[(4 * k4 + 0) * 65 + row] = v.x;
            xs[(4 * k4 + 1) * 65 + row] = v.y;
            xs[(4 * k4 + 2) * 65 + row] = v.z;
            xs[(4 * k4 + 3) * 65 + row] = v.w;
        }
        __syncthreads();
        const float* wb = W1 + (size_t)(h * 64) * HID + wid * 16;
#pragma unroll 4
        for (int k = 0; k < 64; k++) {
            float xv = xs[k * 65 + lane];
            const float* wk = wb + k * HID;
#pragma unroll
            for (int c = 0; c < 16; c++) acc[c] = fmaf(wk[c], xv, acc[c]);
        }
        __syncthreads();
    }
    if (lane < nrows) {
        unsigned pk[8];
#pragma unroll
        for (int j = 0; j < 8; j++)
            pk[j] = (unsigned)f2bf(acc[2 * j]) | ((unsigned)f2bf(acc[2 * j + 1]) << 16);
        uint4* hp = reinterpret_cast<uint4*>(h1 + (size_t)(base + lane) * HID + wid * 16);
        hp[0] = make_uint4(pk[0], pk[1], pk[2], pk[3]);
        hp[1] = make_uint4(pk[4], pk[5], pk[6], pk[7]);
    }
}

// ---------- agg1: y = relu(A@h1 + b1), bf16 in/out (wave per node) ----------
__global__ __launch_bounds__(256) void k_agg1(const unsigned short* __restrict__ h1,
                                              const int* __restrict__ rowptr,
                                              const int2* __restrict__ edges,
                                              const float* __restrict__ dinv,
                                              const float* __restrict__ b1,
                                              unsigned short* __restrict__ y, int n) {
    int lane = threadIdx.x & 63;
    int wid = threadIdx.x >> 6;
    for (int node = blockIdx.x * 4 + wid; node < n; node += gridDim.x * 4) {
        int i = __builtin_amdgcn_readfirstlane(node);
        float di = dinv[i];
        float a0 = di * di * bf2f(h1[(size_t)i * HID + lane]);
        float a1 = 0.f, a2 = 0.f, a3 = 0.f, a4 = 0.f, a5 = 0.f, a6 = 0.f, a7 = 0.f;
        int s = rowptr[i], e = rowptr[i + 1];
        int p = s;
        for (; p + 8 <= e; p += 8) {
            int2 e0 = edges[p], e1 = edges[p + 1], e2 = edges[p + 2], e3 = edges[p + 3];
            int2 e4 = edges[p + 4], e5 = edges[p + 5], e6 = edges[p + 6], e7 = edges[p + 7];
            a0 = fmaf(__int_as_float(e0.y), bf2f(h1[(size_t)e0.x * HID + lane]), a0);
            a1 = fmaf(__int_as_float(e1.y), bf2f(h1[(size_t)e1.x * HID + lane]), a1);
            a2 = fmaf(__int_as_float(e2.y), bf2f(h1[(size_t)e2.x * HID + lane]), a2);
            a3 = fmaf(__int_as_float(e3.y), bf2f(h1[(size_t)e3.x * HID + lane]), a3);
            a4 = fmaf(__int_as_float(e4.y), bf2f(h1[(size_t)e4.x * HID + lane]), a4);
            a5 = fmaf(__int_as_float(e5.y), bf2f(h1[(size_t)e5.x * HID + lane]), a5);
            a6 = fmaf(__int_as_float(e6.y), bf2f(h1[(size_t)e6.x * HID + lane]), a6);
            a7 = fmaf(__int_as_float(e7.y), bf2f(h1[(size_t)e7.x * HID + lane]), a7);
        }
        for (; p + 4 <= e; p += 4) {
            int2 e0 = edges[p], e1 = edges[p + 1], e2 = edges[p + 2], e3 = edges[p + 3];
            a0 = fmaf(__int_as_float(e0.y), bf2f(h1[(size_t)e0.x * HID + lane]), a0);
            a1 = fmaf(__int_as_float(e1.y), bf2f(h1[(size_t)e1.x * HID + lane]), a1);
            a2 = fmaf(__int_as_float(e2.y), bf2f(h1[(size_t)e2.x * HID + lane]), a2);
            a3 = fmaf(__int_as_float(e3.y), bf2f(h1[(size_t)e3.x * HID + lane]), a3);
        }
        for (; p < e; p++) {
            int2 e0 = edges[p];
            a0 = fmaf(__int_as_float(e0.y), bf2f(h1[(size_t)e0.x * HID + lane]), a0);
        }
        float acc = ((a0 + a1) + (a2 + a3)) + ((a4 + a5) + (a6 + a7)) + b1[lane];
        y[(size_t)i * HID + lane] = f2bf(fmaxf(acc, 0.f));
    }
}

// ---------- aggz: z = A@y (bf16 gather, f32 out) ----------
__global__ __launch_bounds__(256) void k_aggz(const unsigned short* __restrict__ y,
                                              const int* __restrict__ rowptr,
                                              const int2* __restrict__ edges,
                                              const float* __restrict__ dinv,
                                              float* __restrict__ z, int n) {
    int lane = threadIdx.x & 63;
    int wid = threadIdx.x >> 6;
    for (int node = blockIdx.x * 4 + wid; node < n; node += gridDim.x * 4) {
        int i = __builtin_amdgcn_readfirstlane(node);
        float di = dinv[i];
        float a0 = di * di * bf2f(y[(size_t)i * HID + lane]);
        float a1 = 0.f, a2 = 0.f, a3 = 0.f, a4 = 0.f, a5 = 0.f, a6 = 0.f, a7 = 0.f;
        int s = rowptr[i], e = rowptr[i + 1];
        int p = s;
        for (; p + 8 <= e; p += 8) {
            int2 e0 = edges[p], e1 = edges[p + 1], e2 = edges[p + 2], e3 = edges[p + 3];
            int2 e4 = edges[p + 4], e5 = edges[p + 5], e6 = edges[p + 6], e7 = edges[p + 7];
            a0 = fmaf(__int_as_float(e0.y), bf2f(y[(size_t)e0.x * HID + lane]), a0);
            a1 = fmaf(__int_as_float(e1.y), bf2f(y[(size_t)e1.x * HID + lane]), a1);
            a2 = fmaf(__int_as_float(e2.y), bf2f(y[(size_t)e2.x * HID + lane]), a2);
            a3 = fmaf(__int_as_float(e3.y), bf2f(y[(size_t)e3.x * HID + lane]), a3);
            a4 = fmaf(__int_as_float(e4.y), bf2f(y[(size_t)e4.x * HID + lane]), a4);
            a5 = fmaf(__int_as_float(e5.y), bf2f(y[(size_t)e5.x * HID + lane]), a5);
            a6 = fmaf(__int_as_float(e6.y), bf2f(y[(size_t)e6.x * HID + lane]), a6);
            a7 = fmaf(__int_as_float(e7.y), bf2f(y[(size_t)e7.x * HID + lane]), a7);
        }
        for (; p + 4 <= e; p += 4) {
            int2 e0 = edges[p], e1 = edges[p + 1], e2 = edges[p + 2], e3 = edges[p + 3];
            a0 = fmaf(__int_as_float(e0.y), bf2f(y[(size_t)e0.x * HID + lane]), a0);
            a1 = fmaf(__int_as_float(e1.y), bf2f(y[(size_t)e1.x * HID + lane]), a1);
            a2 = fmaf(__int_as_float(e2.y), bf2f(y[(size_t)e2.x * HID + lane]), a2);
            a3 = fmaf(__int_as_float(e3.y), bf2f(y[(size_t)e3.x * HID + lane]), a3);
        }
        for (; p < e; p++) {
            int2 e0 = edges[p];
            a0 = fmaf(__int_as_float(e0.y), bf2f(y[(size_t)e0.x * HID + lane]), a0);
        }
        float acc = ((a0 + a1) + (a2 + a3)) + ((a4 + a5) + (a6 + a7));
        z[(size_t)i * HID + lane] = acc;
    }
}

// ---------- gemm2s: out = log_softmax(z @ W2 + b2) (dense, streaming) ----------
__global__ __launch_bounds__(256) void k_gemm2s(const float* __restrict__ z,
                                                const float* __restrict__ W2,
                                                const float* __restrict__ b2,
                                                float* __restrict__ out, int n) {
    __shared__ float ys[HID * 65];      // transposed z tile [k][row]
    __shared__ float zs[64 * 41];       // logits [row][col(40)], stride 41
    int t = threadIdx.x;
    int lane = t & 63;
    int wid = __builtin_amdgcn_readfirstlane(t >> 6);
    int base = blockIdx.x * 64;
    int nrows = n - base; if (nrows > 64) nrows = 64;
    const float4* yg = reinterpret_cast<const float4*>(z + (size_t)base * HID);
    for (int j = t; j < nrows * 16; j += 256) {
        int row = j >> 4, k4 = j & 15;
        float4 v = yg[j];
        ys[(4 * k4 + 0) * 65 + row] = v.x;
        ys[(4 * k4 + 1) * 65 + row] = v.y;
        ys[(4 * k4 + 2) * 65 + row] = v.z;
        ys[(4 * k4 + 3) * 65 + row] = v.w;
    }
    __syncthreads();
    const float* wb = W2 + wid * 10;
    float acc[10];
#pragma unroll
    for (int c = 0; c < 10; c++) acc[c] = b2[wid * 10 + c];
#pragma unroll 4
    for (int k = 0; k < HID; k++) {
        float yv = ys[k * 65 + lane];
        const float* wk = wb + k * NCLS;
#pragma unroll
        for (int c = 0; c < 10; c++) acc[c] = fmaf(wk[c], yv, acc[c]);
    }
#pragma unroll
    for (int c = 0; c < 10; c++) zs[lane * 41 + wid * 10 + c] = acc[c];
    __syncthreads();
    if (lane < nrows) {
        const float* zr = zs + lane * 41;
        float m = zr[0];
#pragma unroll
        for (int j = 1; j < NCLS; j++) m = fmaxf(m, zr[j]);
        float sum = 0.f;
#pragma unroll
        for (int j = 0; j < NCLS; j++) sum += expf(zr[j] - m);
        float lse = m + logf(sum);
        float2* op = reinterpret_cast<float2*>(out + (size_t)(base + lane) * NCLS + wid * 10);
#pragma unroll
        for (int j = 0; j < 5; j++)
            op[j] = make_float2(acc[2 * j] - lse, acc[2 * j + 1] - lse);
    }
}

// ---------------- launch ----------------

extern "C" void kernel_launch(void* const* d_in, const int* in_sizes, int n_in,
                              void* d_out, int out_size, void* d_ws, size_t ws_size,
                              hipStream_t stream) {
    const float* x = (const float*)d_in[0];
    const int* edge_index = (const int*)d_in[1];
    const float* ew = (const float*)d_in[2];
    const float* W1 = (const float*)d_in[3];
    const float* b1 = (const float*)d_in[4];
    const float* W2 = (const float*)d_in[5];
    const float* b2 = (const float*)d_in[6];
    float* out = (float*)d_out;

    const int N = in_sizes[0] / NFEAT;      // 100000
    const int E = in_sizes[2];              // 1600000
    const int* src = edge_index;
    const int* dst = edge_index + E;

    const int NBUK = (N + 127) >> BSH;      // 782
    const int EPB = (E + PB - 1) / PB;      // 3125

    char* ws = (char*)d_ws;
    size_t off = 0;
    auto alloc = [&](size_t bytes) { void* p = ws + off; off = (off + bytes + 255) & ~(size_t)255; return p; };
    int*   ghist    = (int*)alloc((size_t)NBUK_MAX * PB * 4);   // 2 MB
    int*   buktot   = (int*)alloc(4096);
    int*   bukstart = (int*)alloc(4096 + 4);
    int*   rowptr   = (int*)alloc((size_t)(N + 1) * 4);
    float* dinv     = (float*)alloc((size_t)N * 4);
    int2*  edges    = (int2*)alloc((size_t)E * 8);              // 12.8 MB
    unsigned short* ybuf = (unsigned short*)alloc((size_t)N * HID * 2);  // 12.8 MB
    // union region: sedge (build) -> h1 (gemm1/agg1) -> z (aggz/gemm2s); disjoint lifetimes
    void* uni = alloc((size_t)N * HID * 4);                     // 25.6 MB
    unsigned long long* sedge = (unsigned long long*)uni;
    unsigned short* h1 = (unsigned short*)uni;
    float* z = (float*)uni;

    k_hist<<<PB, 256, 0, stream>>>(dst, ghist, E, NBUK, EPB);
    k_colscan<<<NBUK, 256, 0, stream>>>(ghist, buktot, NBUK);
    k_bukscan<<<1, 256, 0, stream>>>(buktot, bukstart, rowptr, NBUK, N, E);
    k_bucketize<<<PB, 256, 0, stream>>>(src, dst, ew, ghist, bukstart, sedge, E, NBUK, EPB);
    k_bucket_csr<<<NBUK, 256, 0, stream>>>(sedge, bukstart, rowptr, dinv, edges, N);
    k_norm<<<NBUK, 256, 0, stream>>>(bukstart, dinv, edges, N);
    k_gemm1<<<(N + 63) / 64, 256, 0, stream>>>(x, W1, h1, N);
    k_agg1<<<(N + 3) / 4, 256, 0, stream>>>(h1, rowptr, edges, dinv, b1, ybuf, N);
    k_aggz<<<(N + 3) / 4, 256, 0, stream>>>(ybuf, rowptr, edges, dinv, z, N);
    k_gemm2s<<<(N + 63) / 64, 256, 0, stream>>>(z, W2, b2, out, N);
}

// Round 10
// 305.242 us; speedup vs baseline: 1.0287x; 1.0287x over previous
//
#include <hip/hip_runtime.h>
#include <hip/hip_bf16.h>
#include <math.h>

// GCN 2-layer: x[N,128] @ W1 -> agg -> relu -> @ W2 -> agg -> log_softmax
// N=100000, E=1600000, F=128, H=64, C=40
// CSR via LDS bucket counting-sort (zero global atomics).
// Layer 2 reordered: A@(y@W2) == (A@y)@W2.
// Agg gathers use 8-groups-of-8-lanes: one dwordx4 instruction fetches 8
// source rows (1KB/wave) -> 8x fewer VMEM instructions than row-per-wave.

#define NFEAT 128
#define HID 64
#define NCLS 40
#define PB 512          // partition blocks for hist/bucketize
#define BSH 7           // 128 nodes per bucket
#define NBUK_MAX 1024

static __device__ __forceinline__ unsigned short f2bf(float f) {
    unsigned u = __float_as_uint(f);
    unsigned r = (u + 0x7fffu + ((u >> 16) & 1u)) >> 16;
    return (unsigned short)r;
}
static __device__ __forceinline__ float bf2f(unsigned short b) {
    return __uint_as_float(((unsigned)b) << 16);
}
static __device__ __forceinline__ float bflo(unsigned u) {
    return __uint_as_float(u << 16);
}
static __device__ __forceinline__ float bfhi(unsigned u) {
    return __uint_as_float(u & 0xffff0000u);
}

// ---------- Pass A: per-block bucket histogram ----------
__global__ __launch_bounds__(256) void k_hist(const int* __restrict__ dst,
                                              int* __restrict__ ghist,
                                              int e, int nbuk, int epb) {
    __shared__ int hist[NBUK_MAX];
    for (int j = threadIdx.x; j < nbuk; j += 256) hist[j] = 0;
    __syncthreads();
    int b = blockIdx.x;
    int lo = b * epb, hi = min(lo + epb, e);
    for (int i = lo + threadIdx.x; i < hi; i += 256)
        atomicAdd(&hist[dst[i] >> BSH], 1);
    __syncthreads();
    for (int j = threadIdx.x; j < nbuk; j += 256) ghist[j * PB + b] = hist[j];
}

// ---------- Pass B1: exclusive scan of each bucket's column (in place) ----------
__global__ __launch_bounds__(256) void k_colscan(int* __restrict__ ghist,
                                                 int* __restrict__ buktot, int nbuk) {
    __shared__ int s[256];
    int k = blockIdx.x, t = threadIdx.x;
    int* col = ghist + k * PB;
    int v0 = col[2 * t], v1 = col[2 * t + 1];
    int sum = v0 + v1;
    s[t] = sum; __syncthreads();
    for (int off = 1; off < 256; off <<= 1) {
        int x = (t >= off) ? s[t - off] : 0;
        __syncthreads();
        s[t] += x;
        __syncthreads();
    }
    int excl = s[t] - sum;
    col[2 * t] = excl;
    col[2 * t + 1] = excl + v0;
    if (t == 255) buktot[k] = s[255];
}

// ---------- Pass B2: scan bucket totals -> bukstart ----------
__global__ __launch_bounds__(256) void k_bukscan(const int* __restrict__ buktot,
                                                 int* __restrict__ bukstart,
                                                 int* __restrict__ rowptr,
                                                 int nbuk, int n, int e) {
    __shared__ int s[256];
    int t = threadIdx.x;
    int v[4]; int sum = 0;
#pragma unroll
    for (int j = 0; j < 4; j++) { int idx = t * 4 + j; v[j] = (idx < nbuk) ? buktot[idx] : 0; sum += v[j]; }
    s[t] = sum; __syncthreads();
    for (int off = 1; off < 256; off <<= 1) {
        int x = (t >= off) ? s[t - off] : 0;
        __syncthreads();
        s[t] += x;
        __syncthreads();
    }
    int excl = s[t] - sum;
#pragma unroll
    for (int j = 0; j < 4; j++) { int idx = t * 4 + j; if (idx < nbuk) bukstart[idx] = excl; excl += v[j]; }
    if (t == 255) bukstart[nbuk] = s[255];
    if (t == 0) rowptr[n] = e;
}

// ---------- Pass C: scatter edges into bucket-sorted order (LDS atomics only) ----------
__global__ __launch_bounds__(256) void k_bucketize(const int* __restrict__ src,
                                                   const int* __restrict__ dst,
                                                   const float* __restrict__ w,
                                                   const int* __restrict__ ghist,
                                                   const int* __restrict__ bukstart,
                                                   unsigned long long* __restrict__ sedge,
                                                   int e, int nbuk, int epb) {
    __shared__ int loff[NBUK_MAX];
    int b = blockIdx.x;
    for (int j = threadIdx.x; j < nbuk; j += 256) loff[j] = bukstart[j] + ghist[j * PB + b];
    __syncthreads();
    int lo = b * epb, hi = min(lo + epb, e);
    for (int i = lo + threadIdx.x; i < hi; i += 256) {
        int d = dst[i], s = src[i];
        int k = d >> BSH;
        int pos = atomicAdd(&loff[k], 1);
        unsigned long long rec = ((unsigned long long)__float_as_uint(w[i]) << 32)
                               | ((unsigned)(d & 127) << 17) | (unsigned)s;
        sedge[pos] = rec;
    }
}

// ---------- Pass D: per-bucket CSR + degree (LDS float adds) ----------
__global__ __launch_bounds__(256) void k_bucket_csr(const unsigned long long* __restrict__ sedge,
                                                    const int* __restrict__ bukstart,
                                                    int* __restrict__ rowptr,
                                                    float* __restrict__ dinv,
                                                    int2* __restrict__ edges, int n) {
    __shared__ int cnt[128]; __shared__ float wsum[128];
    __shared__ int fill[128]; __shared__ int rloc[128];
    int k = blockIdx.x, t = threadIdx.x;
    int base = k << BSH;
    int nloc = n - base; if (nloc > 128) nloc = 128;
    if (t < 128) { cnt[t] = 0; fill[t] = 0; wsum[t] = 1.0f; }   // 1.0 = self-loop weight
    __syncthreads();
    int lo = bukstart[k], hi = bukstart[k + 1];
    for (int p = lo + t; p < hi; p += 256) {
        unsigned long long r = sedge[p];
        int dloc = (int)((r >> 17) & 127);
        atomicAdd(&cnt[dloc], 1);
        atomicAdd(&wsum[dloc], __uint_as_float((unsigned)(r >> 32)));
    }
    __syncthreads();
    if (t < 128) rloc[t] = cnt[t];
    __syncthreads();
    for (int off = 1; off < 128; off <<= 1) {
        int x = 0;
        if (t < 128 && t >= off) x = rloc[t - off];
        __syncthreads();
        if (t < 128) rloc[t] += x;
        __syncthreads();
    }
    if (t < 128) {
        int excl = rloc[t] - cnt[t];
        rloc[t] = excl;
        if (t < nloc) {
            rowptr[base + t] = lo + excl;
            dinv[base + t] = rsqrtf(wsum[t]);   // deg >= 1 (self loop)
        }
    }
    __syncthreads();
    for (int p = lo + t; p < hi; p += 256) {
        unsigned long long r = sedge[p];
        int dloc = (int)((r >> 17) & 127);
        int srcn = (int)(r & 0x1ffff);
        int pos = lo + rloc[dloc] + atomicAdd(&fill[dloc], 1);
        edges[pos] = make_int2((dloc << 17) | srcn, (int)(unsigned)(r >> 32)); // keep dloc+raw w
    }
}

// ---------- Pass E: normalize edge values in place ----------
__global__ __launch_bounds__(256) void k_norm(const int* __restrict__ bukstart,
                                              const float* __restrict__ dinv,
                                              int2* __restrict__ edges, int n) {
    int k = blockIdx.x;
    int base = k << BSH;
    int lo = bukstart[k], hi = bukstart[k + 1];
    for (int p = lo + threadIdx.x; p < hi; p += 256) {
        int2 rec = edges[p];
        int dloc = rec.x >> 17, srcn = rec.x & 0x1ffff;
        float v = __int_as_float(rec.y) * dinv[srcn] * dinv[base + dloc];
        edges[p] = make_int2(srcn, __float_as_int(v));
    }
}

// ---------- GEMM1: 64-row tiles, x transposed in LDS, bf16 output ----------
__global__ __launch_bounds__(256) void k_gemm1(const float* __restrict__ x,
                                               const float* __restrict__ W1,
                                               unsigned short* __restrict__ h1, int n) {
    __shared__ float xs[64 * 65];
    int t = threadIdx.x;
    int lane = t & 63;
    int wid = __builtin_amdgcn_readfirstlane(t >> 6);
    int base = blockIdx.x * 64;
    int nrows = n - base; if (nrows > 64) nrows = 64;
    const float4* xg = reinterpret_cast<const float4*>(x + (size_t)base * NFEAT);
    float acc[16];
#pragma unroll
    for (int c = 0; c < 16; c++) acc[c] = 0.f;
#pragma unroll
    for (int h = 0; h < 2; h++) {
        for (int j = t; j < nrows * 16; j += 256) {
            int row = j >> 4, k4 = j & 15;
            float4 v = xg[row * 32 + h * 16 + k4];
            xs[(4 * k4 + 0) * 65 + row] = v.x;
            xs[(4 * k4 + 1) * 65 + row] = v.y;
            xs[(4 * k4 + 2) * 65 + row] = v.z;
            xs[(4 * k4 + 3) * 65 + row] = v.w;
        }
        __syncthreads();
        const float* wb = W1 + (size_t)(h * 64) * HID + wid * 16;
#pragma unroll 4
        for (int k = 0; k < 64; k++) {
            float xv = xs[k * 65 + lane];
            const float* wk = wb + k * HID;
#pragma unroll
            for (int c = 0; c < 16; c++) acc[c] = fmaf(wk[c], xv, acc[c]);
        }
        __syncthreads();
    }
    if (lane < nrows) {
        unsigned pk[8];
#pragma unroll
        for (int j = 0; j < 8; j++)
            pk[j] = (unsigned)f2bf(acc[2 * j]) | ((unsigned)f2bf(acc[2 * j + 1]) << 16);
        uint4* hp = reinterpret_cast<uint4*>(h1 + (size_t)(base + lane) * HID + wid * 16);
        hp[0] = make_uint4(pk[0], pk[1], pk[2], pk[3]);
        hp[1] = make_uint4(pk[4], pk[5], pk[6], pk[7]);
    }
}

#define FMA8(acc, v, r)                                   \
    acc[0] = fmaf(v, bflo(r.x), acc[0]);                  \
    acc[1] = fmaf(v, bfhi(r.x), acc[1]);                  \
    acc[2] = fmaf(v, bflo(r.y), acc[2]);                  \
    acc[3] = fmaf(v, bfhi(r.y), acc[3]);                  \
    acc[4] = fmaf(v, bflo(r.z), acc[4]);                  \
    acc[5] = fmaf(v, bfhi(r.z), acc[5]);                  \
    acc[6] = fmaf(v, bflo(r.w), acc[6]);                  \
    acc[7] = fmaf(v, bfhi(r.w), acc[7]);

// ---------- agg1: y = relu(A@h1 + b1), 8 groups x 8 lanes wide-gather ----------
__global__ __launch_bounds__(256) void k_agg1(const unsigned short* __restrict__ h1,
                                              const int* __restrict__ rowptr,
                                              const int2* __restrict__ edges,
                                              const float* __restrict__ dinv,
                                              const float* __restrict__ b1,
                                              unsigned short* __restrict__ y, int n) {
    int lane = threadIdx.x & 63;
    int wid = threadIdx.x >> 6;
    int g = lane >> 3;       // edge group 0..7
    int sl = lane & 7;       // 16B slice of row
    // per-lane bias slice b1[sl*8 .. sl*8+8)
    const float4* bp = reinterpret_cast<const float4*>(b1 + sl * 8);
    float4 bA = bp[0], bB = bp[1];
    float bcol[8] = {bA.x, bA.y, bA.z, bA.w, bB.x, bB.y, bB.z, bB.w};

    for (int node = blockIdx.x * 4 + wid; node < n; node += gridDim.x * 4) {
        int i = __builtin_amdgcn_readfirstlane(node);
        float di = dinv[i];
        float acc[8];
#pragma unroll
        for (int j = 0; j < 8; j++) acc[j] = 0.f;
        if (g == 0) {
            uint4 r = *reinterpret_cast<const uint4*>(h1 + (size_t)i * HID + sl * 8);
            float s2 = di * di;
            FMA8(acc, s2, r);
        }
        int s = rowptr[i], e = rowptr[i + 1];
        int p = s;
        for (; p + 16 <= e; p += 16) {
            int2 erA = edges[p + g];
            int2 erB = edges[p + 8 + g];
            uint4 ra = *reinterpret_cast<const uint4*>(h1 + (size_t)erA.x * HID + sl * 8);
            uint4 rb = *reinterpret_cast<const uint4*>(h1 + (size_t)erB.x * HID + sl * 8);
            float va = __int_as_float(erA.y);
            float vb = __int_as_float(erB.y);
            FMA8(acc, va, ra);
            FMA8(acc, vb, rb);
        }
        for (; p < e; p += 8) {
            int pe = p + g;
            int2 er = (pe < e) ? edges[pe] : make_int2(i, 0);
            uint4 r = *reinterpret_cast<const uint4*>(h1 + (size_t)er.x * HID + sl * 8);
            float v = __int_as_float(er.y);
            FMA8(acc, v, r);
        }
        // reduce across the 8 groups (lanes with same sl)
#pragma unroll
        for (int off = 8; off <= 32; off <<= 1) {
#pragma unroll
            for (int j = 0; j < 8; j++) acc[j] += __shfl_xor(acc[j], off);
        }
        if (g == 0) {
            unsigned pk[4];
#pragma unroll
            for (int j = 0; j < 4; j++) {
                float f0 = fmaxf(acc[2 * j] + bcol[2 * j], 0.f);
                float f1 = fmaxf(acc[2 * j + 1] + bcol[2 * j + 1], 0.f);
                pk[j] = (unsigned)f2bf(f0) | ((unsigned)f2bf(f1) << 16);
            }
            *reinterpret_cast<uint4*>(y + (size_t)i * HID + sl * 8) =
                make_uint4(pk[0], pk[1], pk[2], pk[3]);
        }
    }
}

// ---------- aggz: z = A@y, same wide-gather, f32 out ----------
__global__ __launch_bounds__(256) void k_aggz(const unsigned short* __restrict__ y,
                                              const int* __restrict__ rowptr,
                                              const int2* __restrict__ edges,
                                              const float* __restrict__ dinv,
                                              float* __restrict__ z, int n) {
    int lane = threadIdx.x & 63;
    int wid = threadIdx.x >> 6;
    int g = lane >> 3;
    int sl = lane & 7;
    for (int node = blockIdx.x * 4 + wid; node < n; node += gridDim.x * 4) {
        int i = __builtin_amdgcn_readfirstlane(node);
        float di = dinv[i];
        float acc[8];
#pragma unroll
        for (int j = 0; j < 8; j++) acc[j] = 0.f;
        if (g == 0) {
            uint4 r = *reinterpret_cast<const uint4*>(y + (size_t)i * HID + sl * 8);
            float s2 = di * di;
            FMA8(acc, s2, r);
        }
        int s = rowptr[i], e = rowptr[i + 1];
        int p = s;
        for (; p + 16 <= e; p += 16) {
            int2 erA = edges[p + g];
            int2 erB = edges[p + 8 + g];
            uint4 ra = *reinterpret_cast<const uint4*>(y + (size_t)erA.x * HID + sl * 8);
            uint4 rb = *reinterpret_cast<const uint4*>(y + (size_t)erB.x * HID + sl * 8);
            float va = __int_as_float(erA.y);
            float vb = __int_as_float(erB.y);
            FMA8(acc, va, ra);
            FMA8(acc, vb, rb);
        }
        for (; p < e; p += 8) {
            int pe = p + g;
            int2 er = (pe < e) ? edges[pe] : make_int2(i, 0);
            uint4 r = *reinterpret_cast<const uint4*>(y + (size_t)er.x * HID + sl * 8);
            float v = __int_as_float(er.y);
            FMA8(acc, v, r);
        }
#pragma unroll
        for (int off = 8; off <= 32; off <<= 1) {
#pragma unroll
            for (int j = 0; j < 8; j++) acc[j] += __shfl_xor(acc[j], off);
        }
        if (g == 0) {
            float* zp = z + (size_t)i * HID + sl * 8;
            *reinterpret_cast<float4*>(zp) = make_float4(acc[0], acc[1], acc[2], acc[3]);
            *reinterpret_cast<float4*>(zp + 4) = make_float4(acc[4], acc[5], acc[6], acc[7]);
        }
    }
}

// ---------- gemm2s: out = log_softmax(z @ W2 + b2) (dense, streaming) ----------
__global__ __launch_bounds__(256) void k_gemm2s(const float* __restrict__ z,
                                                const float* __restrict__ W2,
                                                const float* __restrict__ b2,
                                                float* __restrict__ out, int n) {
    __shared__ float ys[HID * 65];      // transposed z tile [k][row]
    __shared__ float zs[64 * 41];       // logits [row][col(40)], stride 41
    int t = threadIdx.x;
    int lane = t & 63;
    int wid = __builtin_amdgcn_readfirstlane(t >> 6);
    int base = blockIdx.x * 64;
    int nrows = n - base; if (nrows > 64) nrows = 64;
    const float4* yg = reinterpret_cast<const float4*>(z + (size_t)base * HID);
    for (int j = t; j < nrows * 16; j += 256) {
        int row = j >> 4, k4 = j & 15;
        float4 v = yg[j];
        ys[(4 * k4 + 0) * 65 + row] = v.x;
        ys[(4 * k4 + 1) * 65 + row] = v.y;
        ys[(4 * k4 + 2) * 65 + row] = v.z;
        ys[(4 * k4 + 3) * 65 + row] = v.w;
    }
    __syncthreads();
    const float* wb = W2 + wid * 10;
    float acc[10];
#pragma unroll
    for (int c = 0; c < 10; c++) acc[c] = b2[wid * 10 + c];
#pragma unroll 4
    for (int k = 0; k < HID; k++) {
        float yv = ys[k * 65 + lane];
        const float* wk = wb + k * NCLS;
#pragma unroll
        for (int c = 0; c < 10; c++) acc[c] = fmaf(wk[c], yv, acc[c]);
    }
#pragma unroll
    for (int c = 0; c < 10; c++) zs[lane * 41 + wid * 10 + c] = acc[c];
    __syncthreads();
    if (lane < nrows) {
        const float* zr = zs + lane * 41;
        float m = zr[0];
#pragma unroll
        for (int j = 1; j < NCLS; j++) m = fmaxf(m, zr[j]);
        float sum = 0.f;
#pragma unroll
        for (int j = 0; j < NCLS; j++) sum += expf(zr[j] - m);
        float lse = m + logf(sum);
        float2* op = reinterpret_cast<float2*>(out + (size_t)(base + lane) * NCLS + wid * 10);
#pragma unroll
        for (int j = 0; j < 5; j++)
            op[j] = make_float2(acc[2 * j] - lse, acc[2 * j + 1] - lse);
    }
}

// ---------------- launch ----------------

extern "C" void kernel_launch(void* const* d_in, const int* in_sizes, int n_in,
                              void* d_out, int out_size, void* d_ws, size_t ws_size,
                              hipStream_t stream) {
    const float* x = (const float*)d_in[0];
    const int* edge_index = (const int*)d_in[1];
    const float* ew = (const float*)d_in[2];
    const float* W1 = (const float*)d_in[3];
    const float* b1 = (const float*)d_in[4];
    const float* W2 = (const float*)d_in[5];
    const float* b2 = (const float*)d_in[6];
    float* out = (float*)d_out;

    const int N = in_sizes[0] / NFEAT;      // 100000
    const int E = in_sizes[2];              // 1600000
    const int* src = edge_index;
    const int* dst = edge_index + E;

    const int NBUK = (N + 127) >> BSH;      // 782
    const int EPB = (E + PB - 1) / PB;      // 3125

    char* ws = (char*)d_ws;
    size_t off = 0;
    auto alloc = [&](size_t bytes) { void* p = ws + off; off = (off + bytes + 255) & ~(size_t)255; return p; };
    int*   ghist    = (int*)alloc((size_t)NBUK_MAX * PB * 4);   // 2 MB
    int*   buktot   = (int*)alloc(4096);
    int*   bukstart = (int*)alloc(4096 + 4);
    int*   rowptr   = (int*)alloc((size_t)(N + 1) * 4);
    float* dinv     = (float*)alloc((size_t)N * 4);
    int2*  edges    = (int2*)alloc((size_t)E * 8);              // 12.8 MB
    unsigned short* ybuf = (unsigned short*)alloc((size_t)N * HID * 2);  // 12.8 MB
    // union region: sedge (build) -> h1 (gemm1/agg1) -> z (aggz/gemm2s); disjoint lifetimes
    void* uni = alloc((size_t)N * HID * 4);                     // 25.6 MB
    unsigned long long* sedge = (unsigned long long*)uni;
    unsigned short* h1 = (unsigned short*)uni;
    float* z = (float*)uni;

    k_hist<<<PB, 256, 0, stream>>>(dst, ghist, E, NBUK, EPB);
    k_colscan<<<NBUK, 256, 0, stream>>>(ghist, buktot, NBUK);
    k_bukscan<<<1, 256, 0, stream>>>(buktot, bukstart, rowptr, NBUK, N, E);
    k_bucketize<<<PB, 256, 0, stream>>>(src, dst, ew, ghist, bukstart, sedge, E, NBUK, EPB);
    k_bucket_csr<<<NBUK, 256, 0, stream>>>(sedge, bukstart, rowptr, dinv, edges, N);
    k_norm<<<NBUK, 256, 0, stream>>>(bukstart, dinv, edges, N);
    k_gemm1<<<(N + 63) / 64, 256, 0, stream>>>(x, W1, h1, N);
    k_agg1<<<(N + 3) / 4, 256, 0, stream>>>(h1, rowptr, edges, dinv, b1, ybuf, N);
    k_aggz<<<(N + 3) / 4, 256, 0, stream>>>(ybuf, rowptr, edges, dinv, z, N);
    k_gemm2s<<<(N + 63) / 64, 256, 0, stream>>>(z, W2, b2, out, N);
}